// Round 10
// baseline (5542.382 us; speedup 1.0000x reference)
//
#include <hip/hip_runtime.h>

typedef unsigned short u16;
typedef unsigned long long u64;
typedef __attribute__((ext_vector_type(8))) short short8;
typedef __attribute__((ext_vector_type(4))) float f32x4;

#define HH 1024
#define BB 64
#define TT 512
#define G3 3072
#define NBLK 192
#define NS 513                 // h time-slots (renamed buffers)
#define SLOT (BB * HH)         // elems per h slot
#define FSTRIDE 32             // flag padding: one 128B line per block

__device__ __forceinline__ u16 f2b(float f) {
  unsigned u = __float_as_uint(f);
  unsigned r = (u + 0x7fffu + ((u >> 16) & 1u)) >> 16;
  return (u16)r;
}
__device__ __forceinline__ float b2f(u16 h) {
  return __uint_as_float(((unsigned)h) << 16);
}

__device__ __forceinline__ void st_u32_agent(unsigned* p, unsigned v) {
  __hip_atomic_store(p, v, __ATOMIC_RELAXED, __HIP_MEMORY_SCOPE_AGENT);
}
__device__ __forceinline__ unsigned ld_u32_agent(const unsigned* p) {
  return __hip_atomic_load(p, __ATOMIC_RELAXED, __HIP_MEMORY_SCOPE_AGENT);
}

// ---------------- elementwise converts / init ----------------

__global__ void f32_to_bf16_k(const float* __restrict__ s, u16* __restrict__ d, int n) {
  int stride = gridDim.x * blockDim.x * 4;
  for (int i = (blockIdx.x * blockDim.x + threadIdx.x) * 4; i < n; i += stride) {
    float4 v = *(const float4*)(s + i);
    uint2 p;
    p.x = (unsigned)f2b(v.x) | ((unsigned)f2b(v.y) << 16);
    p.y = (unsigned)f2b(v.z) | ((unsigned)f2b(v.w) << 16);
    *(uint2*)(d + i) = p;
  }
}

__global__ void init_h_k(const float* __restrict__ h0in, u16* __restrict__ hbuf0,
                         u16* __restrict__ hbuf1) {
  int i = blockIdx.x * blockDim.x + threadIdx.x;
  if (i < BB * HH) {
    hbuf0[i] = f2b(h0in[i]);            // slot 0 = H0(0)
    hbuf1[i] = f2b(h0in[BB * HH + i]);  // slot 0 = H1(0)
  }
}

// ---------------- phase A: xg0 = bf16(x @ W_ih0^T + b_ih0) ----------------

__global__ __launch_bounds__(256) void gemm_xg_k(
    const u16* __restrict__ A, const u16* __restrict__ Wt,
    const float* __restrict__ bias, u16* __restrict__ C) {
  const int bm = blockIdx.x / 24;
  const int bn = blockIdx.x % 24;
  const int m0 = bm * 128, n0 = bn * 128;
  __shared__ __align__(16) u16 al[128 * 40];
  __shared__ __align__(16) u16 bl[128 * 40];
  const int tid = threadIdx.x;
  const int w = tid >> 6, l = tid & 63;
  const int wr = w >> 1, wc = w & 1;
  const int c0 = tid, c1 = tid + 256;
  const int r0 = c0 >> 2, s0 = c0 & 3, r1 = c1 >> 2, s1 = c1 & 3;

  const f32x4 fzero = {0.f, 0.f, 0.f, 0.f};
  f32x4 acc[4][4];
#pragma unroll
  for (int i = 0; i < 4; ++i)
#pragma unroll
    for (int j = 0; j < 4; ++j) acc[i][j] = fzero;

  const u16* a0p = A + (size_t)(m0 + r0) * 1024 + s0 * 8;
  const u16* a1p = A + (size_t)(m0 + r1) * 1024 + s1 * 8;
  const u16* b0p = Wt + (size_t)(n0 + r0) * 1024 + s0 * 8;
  const u16* b1p = Wt + (size_t)(n0 + r1) * 1024 + s1 * 8;

  int4 va0 = *(const int4*)(a0p);
  int4 va1 = *(const int4*)(a1p);
  int4 vb0 = *(const int4*)(b0p);
  int4 vb1 = *(const int4*)(b1p);

  for (int kt = 0; kt < 32; ++kt) {
    __syncthreads();
    *(int4*)&al[r0 * 40 + s0 * 8] = va0;
    *(int4*)&al[r1 * 40 + s1 * 8] = va1;
    *(int4*)&bl[r0 * 40 + s0 * 8] = vb0;
    *(int4*)&bl[r1 * 40 + s1 * 8] = vb1;
    __syncthreads();
    if (kt < 31) {
      va0 = *(const int4*)(a0p + (kt + 1) * 32);
      va1 = *(const int4*)(a1p + (kt + 1) * 32);
      vb0 = *(const int4*)(b0p + (kt + 1) * 32);
      vb1 = *(const int4*)(b1p + (kt + 1) * 32);
    }
    short8 af[4], bf[4];
#pragma unroll
    for (int i = 0; i < 4; ++i)
      af[i] = *(const short8*)&al[(wr * 64 + i * 16 + (l & 15)) * 40 + (l >> 4) * 8];
#pragma unroll
    for (int j = 0; j < 4; ++j)
      bf[j] = *(const short8*)&bl[(wc * 64 + j * 16 + (l & 15)) * 40 + (l >> 4) * 8];
#pragma unroll
    for (int i = 0; i < 4; ++i)
#pragma unroll
      for (int j = 0; j < 4; ++j)
        acc[i][j] = __builtin_amdgcn_mfma_f32_16x16x32_bf16(af[i], bf[j], acc[i][j], 0, 0, 0);
  }

#pragma unroll
  for (int i = 0; i < 4; ++i) {
#pragma unroll
    for (int j = 0; j < 4; ++j) {
      int col = n0 + wc * 64 + j * 16 + (l & 15);
      float bv = bias[col];
#pragma unroll
      for (int q = 0; q < 4; ++q) {
        int row = m0 + wr * 64 + i * 16 + (l >> 4) * 4 + q;
        C[(size_t)row * G3 + col] = f2b(acc[i][j][q] + bv);
      }
    }
  }
}

// ---------------- persistent fused scan, v9: decoupled epochs ----------------
// No global barrier. Dataflow sync on renamed slots:
//  part0 (blk 0..63, 16 cols):  t=0..511, reads hbuf0[t] (needs flags0>=t),
//        writes hbuf0[t+1], then flags0[blk]=t+1. Never waits on part2 ->
//        runs ahead (renamed slots, no reuse, no staleness).
//  part2 (blk 64..191, 8 cols): t=1..512, needs flags0>=t (usually already
//        satisfied) and flags2>=t-1; computes xg1 on the fly (ih GEMM vs
//        hbuf0[t]) + hh GEMM vs hbuf1[t-1]; writes hbuf1[t]; flags2[blk]=t.
// Both A-batches issued before the MFMA loops (one exposed LLC latency).
// flags: one padded 128B line per block; flags0 = [0..63], flags2 = [64..191].

__global__ __launch_bounds__(256, 1) void gru_scan9_k(
    const u16* __restrict__ xg0,
    const u16* __restrict__ whh0, const u16* __restrict__ wih1,
    const u16* __restrict__ whh1,
    const float* __restrict__ bhh0, const float* __restrict__ bih1,
    const float* __restrict__ bhh1,
    const float* __restrict__ h0in,
    u16* __restrict__ hbuf0, u16* __restrict__ hbuf1,
    float* __restrict__ out, unsigned* __restrict__ flags) {
  const int blk = blockIdx.x;
  const int part0 = (blk < 64);
  const int tid = threadIdx.x;
  const int w = tid >> 6, l = tid & 63;
  const int lrow = l & 15;
  const int lr7 = lrow & 7;
  const int kb = (l >> 4) * 8;
  const int myrow0 = w * 16 + (l >> 4) * 4;  // batch rows myrow0..+3
  const size_t arow = (size_t)(w * 16 + lrow) * HH + kb;
  const f32x4 fzero = {0.f, 0.f, 0.f, 0.f};

  __shared__ __align__(16) u16 wlds[48 * 1024];

  if (part0) {
    const int sub = blk;
    const int j = sub * 16 + lrow;
    for (int i = tid; i < 6144; i += 256) {
      int r = i >> 7;
      int c = i & 127;
      int g = r >> 4;
      int wrow = g * HH + sub * 16 + (r & 15);
      int4 v = *(const int4*)(whh0 + (size_t)wrow * 1024 + c * 8);
      int idx = r * 1024 + ((c * 8) ^ ((r & 7) << 3));
      *(int4*)&wlds[idx] = v;
    }
    const float bhr = bhh0[j], bhz = bhh0[HH + j], bhn = bhh0[2 * HH + j];
    float hreg[4];
#pragma unroll
    for (int q = 0; q < 4; ++q) hreg[q] = h0in[(myrow0 + q) * HH + j];
    __syncthreads();
    const int sx = lr7 << 3;

    for (int t = 0; t < TT; ++t) {
      if (t > 0) {
        if (tid < 64) {
          for (;;) {
            unsigned a0 = ld_u32_agent(&flags[l * FSTRIDE]);
            if (__all(a0 >= (unsigned)t)) break;
            __builtin_amdgcn_s_sleep(1);
          }
        }
        __syncthreads();
        __builtin_amdgcn_fence(__ATOMIC_ACQUIRE, "workgroup");
      }

      const u16* Ap = hbuf0 + (size_t)t * SLOT + arow;
      short8 ar[32];
#pragma unroll
      for (int ks = 0; ks < 32; ++ks) ar[ks] = *(const short8*)(Ap + ks * 32);

      u16 xrv[4], xzv[4], xnv[4];
      const u16* xp = xg0 + (size_t)t * BB * G3;
#pragma unroll
      for (int q = 0; q < 4; ++q) {
        const u16* rp = xp + (size_t)(myrow0 + q) * G3;
        xrv[q] = rp[j]; xzv[q] = rp[HH + j]; xnv[q] = rp[2 * HH + j];
      }

      f32x4 acc0 = fzero, acc1 = fzero, acc2 = fzero;
#pragma unroll
      for (int ks = 0; ks < 32; ++ks) {
        int ke = kb + ks * 32;
        short8 b0 = *(const short8*)&wlds[(lrow) * 1024 + (ke ^ sx)];
        short8 b1 = *(const short8*)&wlds[(16 + lrow) * 1024 + (ke ^ sx)];
        short8 b2 = *(const short8*)&wlds[(32 + lrow) * 1024 + (ke ^ sx)];
        acc0 = __builtin_amdgcn_mfma_f32_16x16x32_bf16(ar[ks], b0, acc0, 0, 0, 0);
        acc1 = __builtin_amdgcn_mfma_f32_16x16x32_bf16(ar[ks], b1, acc1, 0, 0, 0);
        acc2 = __builtin_amdgcn_mfma_f32_16x16x32_bf16(ar[ks], b2, acc2, 0, 0, 0);
      }

      u16* hbn = hbuf0 + (size_t)(t + 1) * SLOT;
#pragma unroll
      for (int q = 0; q < 4; ++q) {
        float rr = acc0[q] + bhr + b2f(xrv[q]);
        float zz = acc1[q] + bhz + b2f(xzv[q]);
        float nn = acc2[q] + bhn;
        float r = 1.f / (1.f + __expf(-rr));
        float z = 1.f / (1.f + __expf(-zz));
        float n = tanhf(b2f(xnv[q]) + r * nn);
        float hv = (1.f - z) * n + z * hreg[q];
        hreg[q] = hv;
        int hb = (int)f2b(hv);
        int nb = __shfl_xor(hb, 1);
        if ((l & 1) == 0) {
          unsigned pk = (unsigned)(u16)hb | (((unsigned)(u16)nb) << 16);
          st_u32_agent((unsigned*)(hbn + (size_t)(myrow0 + q) * HH + j), pk);
        }
      }

      __syncthreads();  // drain all waves' sc1 stores (vmcnt 0 before barrier)
      if (tid == 0) {
        __builtin_amdgcn_fence(__ATOMIC_RELEASE, "workgroup");
        st_u32_agent(&flags[blk * FSTRIDE], (unsigned)(t + 1));
      }
    }
#pragma unroll
    for (int q = 0; q < 4; ++q) out[(size_t)(myrow0 + q) * HH + j] = hreg[q];

  } else {
    const int sub = blk - 64;
    const bool valid = (lrow < 8);
    const int j = sub * 8 + (valid ? lrow : 0);
    // rows 0..23 = whh1 (3 gates x 8), rows 24..47 = wih1 (3 gates x 8)
    for (int i = tid; i < 6144; i += 256) {
      int r = i >> 7;
      int c = i & 127;
      int half = r >= 24;
      int rr = half ? r - 24 : r;
      int g = rr >> 3;
      const u16* src = half ? wih1 : whh1;
      int wrow = g * HH + sub * 8 + (rr & 7);
      int4 v = *(const int4*)(src + (size_t)wrow * 1024 + c * 8);
      int idx = r * 1024 + ((c * 8) ^ ((r & 7) << 3));
      *(int4*)&wlds[idx] = v;
    }
    const float bhr = bhh1[j], bhz = bhh1[HH + j], bhn = bhh1[2 * HH + j];
    const float bir = bih1[j], biz = bih1[HH + j], bin = bih1[2 * HH + j];
    float hreg[4];
#pragma unroll
    for (int q = 0; q < 4; ++q) hreg[q] = h0in[BB * HH + (myrow0 + q) * HH + j];
    __syncthreads();
    const int sx = lr7 << 3;

    for (int t = 1; t <= TT; ++t) {
      if (tid < 64) {
        for (;;) {
          unsigned a0 = ld_u32_agent(&flags[l * FSTRIDE]);
          unsigned a1 = ld_u32_agent(&flags[(64 + l) * FSTRIDE]);
          unsigned a2 = ld_u32_agent(&flags[(128 + l) * FSTRIDE]);
          unsigned mn = a1 < a2 ? a1 : a2;
          int ok = (a0 >= (unsigned)t) && (mn >= (unsigned)(t - 1));
          if (__all(ok)) break;
          __builtin_amdgcn_s_sleep(1);
        }
      }
      __syncthreads();
      __builtin_amdgcn_fence(__ATOMIC_ACQUIRE, "workgroup");

      // issue BOTH A batches up front (one exposed latency)
      const u16* Ai = hbuf0 + (size_t)t * SLOT + arow;
      const u16* Ah = hbuf1 + (size_t)(t - 1) * SLOT + arow;
      short8 ai[32], ah[32];
#pragma unroll
      for (int ks = 0; ks < 32; ++ks) ai[ks] = *(const short8*)(Ai + ks * 32);
#pragma unroll
      for (int ks = 0; ks < 32; ++ks) ah[ks] = *(const short8*)(Ah + ks * 32);

      f32x4 xri = fzero, xzi = fzero, xni = fzero;
#pragma unroll
      for (int ks = 0; ks < 32; ++ks) {
        int ke = kb + ks * 32;
        short8 b0 = *(const short8*)&wlds[(24 + lr7) * 1024 + (ke ^ sx)];
        short8 b1 = *(const short8*)&wlds[(32 + lr7) * 1024 + (ke ^ sx)];
        short8 b2 = *(const short8*)&wlds[(40 + lr7) * 1024 + (ke ^ sx)];
        xri = __builtin_amdgcn_mfma_f32_16x16x32_bf16(ai[ks], b0, xri, 0, 0, 0);
        xzi = __builtin_amdgcn_mfma_f32_16x16x32_bf16(ai[ks], b1, xzi, 0, 0, 0);
        xni = __builtin_amdgcn_mfma_f32_16x16x32_bf16(ai[ks], b2, xni, 0, 0, 0);
      }
      f32x4 hri = fzero, hzi = fzero, hni = fzero;
#pragma unroll
      for (int ks = 0; ks < 32; ++ks) {
        int ke = kb + ks * 32;
        short8 b0 = *(const short8*)&wlds[(0 + lr7) * 1024 + (ke ^ sx)];
        short8 b1 = *(const short8*)&wlds[(8 + lr7) * 1024 + (ke ^ sx)];
        short8 b2 = *(const short8*)&wlds[(16 + lr7) * 1024 + (ke ^ sx)];
        hri = __builtin_amdgcn_mfma_f32_16x16x32_bf16(ah[ks], b0, hri, 0, 0, 0);
        hzi = __builtin_amdgcn_mfma_f32_16x16x32_bf16(ah[ks], b1, hzi, 0, 0, 0);
        hni = __builtin_amdgcn_mfma_f32_16x16x32_bf16(ah[ks], b2, hni, 0, 0, 0);
      }

      u16* hbn = hbuf1 + (size_t)t * SLOT;
#pragma unroll
      for (int q = 0; q < 4; ++q) {
        float rr = (xri[q] + bir) + (hri[q] + bhr);
        float zz = (xzi[q] + biz) + (hzi[q] + bhz);
        float nn = hni[q] + bhn;
        float r = 1.f / (1.f + __expf(-rr));
        float z = 1.f / (1.f + __expf(-zz));
        float n = tanhf((xni[q] + bin) + r * nn);
        float hv = (1.f - z) * n + z * hreg[q];
        hreg[q] = hv;
        int hb = (int)f2b(hv);
        int nb = __shfl_xor(hb, 1);
        if (valid && (l & 1) == 0) {
          unsigned pk = (unsigned)(u16)hb | (((unsigned)(u16)nb) << 16);
          st_u32_agent((unsigned*)(hbn + (size_t)(myrow0 + q) * HH + j), pk);
        }
      }

      __syncthreads();  // drain sc1 stores
      if (tid == 0) {
        __builtin_amdgcn_fence(__ATOMIC_RELEASE, "workgroup");
        st_u32_agent(&flags[blk * FSTRIDE], (unsigned)t);
      }
    }
    if (valid) {
#pragma unroll
      for (int q = 0; q < 4; ++q) out[BB * HH + (size_t)(myrow0 + q) * HH + j] = hreg[q];
    }
  }
}

// ---------------- host ----------------

extern "C" void kernel_launch(void* const* d_in, const int* in_sizes, int n_in,
                              void* d_out, int out_size, void* d_ws, size_t ws_size,
                              hipStream_t stream) {
  const float* x   = (const float*)d_in[0];
  const float* h0  = (const float*)d_in[1];
  const float* wih = (const float*)d_in[2];
  const float* whh = (const float*)d_in[3];
  const float* bih = (const float*)d_in[4];
  const float* bhh = (const float*)d_in[5];
  float* out = (float*)d_out;

  char* ws = (char*)d_ws;
  size_t off = 0;
  auto alloc = [&](size_t bytes) -> void* {
    void* p = ws + off;
    off += (bytes + 255) & ~(size_t)255;
    return p;
  };
  u16* xg0   = (u16*)alloc((size_t)TT * BB * G3 * 2);        // 193 MB
  u16* wihb  = (u16*)alloc((size_t)2 * G3 * HH * 2);         // 12.6 MB
  u16* whhb  = (u16*)alloc((size_t)2 * G3 * HH * 2);         // 12.6 MB
  // union: xbf (64 MB, dead after gemm) overlaid by hbuf0/hbuf1 (134.5 MB)
  size_t hbytes = (size_t)2 * NS * SLOT * 2;
  size_t xbytes = (size_t)TT * BB * HH * 2;
  char* un = (char*)alloc(hbytes > xbytes ? hbytes : xbytes);
  u16* xbf   = (u16*)un;
  u16* hbuf0 = (u16*)un;
  u16* hbuf1 = hbuf0 + (size_t)NS * SLOT;
  unsigned* flags = (unsigned*)alloc(NBLK * FSTRIDE * 4);

  hipMemsetAsync(flags, 0, NBLK * FSTRIDE * 4, stream);
  f32_to_bf16_k<<<2048, 256, 0, stream>>>(x, xbf, TT * BB * HH);
  f32_to_bf16_k<<<512, 256, 0, stream>>>(wih, wihb, 2 * G3 * HH);
  f32_to_bf16_k<<<512, 256, 0, stream>>>(whh, whhb, 2 * G3 * HH);

  gemm_xg_k<<<6144, 256, 0, stream>>>(xbf, wihb, bih, xg0);

  // init h AFTER gemm: hbuf aliases xbf
  init_h_k<<<256, 256, 0, stream>>>(h0, hbuf0, hbuf1);

  gru_scan9_k<<<NBLK, 256, 0, stream>>>(xg0,
                                        whhb, wihb + (size_t)G3 * HH, whhb + (size_t)G3 * HH,
                                        bhh, bih + G3, bhh + G3, h0,
                                        hbuf0, hbuf1, out, flags);
}

// Round 11
// 4465.327 us; speedup vs baseline: 1.2412x; 1.2412x over previous
//
#include <hip/hip_runtime.h>

typedef unsigned short u16;
typedef unsigned long long u64;
typedef __attribute__((ext_vector_type(8))) short short8;
typedef __attribute__((ext_vector_type(4))) float f32x4;

#define HH 1024
#define BB 64
#define TT 512
#define G3 3072
#define NBLK 192
#define NS 513                 // h time-slots (renamed buffers)
#define SLOT (BB * HH)         // elems per h slot
#define FSTRIDE 32             // flag padding: one 128B line per block
#define RING 8                 // xg1 ring depth

__device__ __forceinline__ u16 f2b(float f) {
  unsigned u = __float_as_uint(f);
  unsigned r = (u + 0x7fffu + ((u >> 16) & 1u)) >> 16;
  return (u16)r;
}
__device__ __forceinline__ float b2f(u16 h) {
  return __uint_as_float(((unsigned)h) << 16);
}
__device__ __forceinline__ float ftanh(float x) {
  x = fminf(15.f, fmaxf(-15.f, x));
  float e = __expf(2.f * x);
  return (e - 1.f) / (e + 1.f);
}

__device__ __forceinline__ void st_u32_agent(unsigned* p, unsigned v) {
  __hip_atomic_store(p, v, __ATOMIC_RELAXED, __HIP_MEMORY_SCOPE_AGENT);
}
__device__ __forceinline__ unsigned ld_u32_agent(const unsigned* p) {
  return __hip_atomic_load(p, __ATOMIC_RELAXED, __HIP_MEMORY_SCOPE_AGENT);
}

// ---------------- elementwise converts / init ----------------

__global__ void f32_to_bf16_k(const float* __restrict__ s, u16* __restrict__ d, int n) {
  int stride = gridDim.x * blockDim.x * 4;
  for (int i = (blockIdx.x * blockDim.x + threadIdx.x) * 4; i < n; i += stride) {
    float4 v = *(const float4*)(s + i);
    uint2 p;
    p.x = (unsigned)f2b(v.x) | ((unsigned)f2b(v.y) << 16);
    p.y = (unsigned)f2b(v.z) | ((unsigned)f2b(v.w) << 16);
    *(uint2*)(d + i) = p;
  }
}

__global__ void init_h_k(const float* __restrict__ h0in, u16* __restrict__ hbuf0,
                         u16* __restrict__ hbuf1) {
  int i = blockIdx.x * blockDim.x + threadIdx.x;
  if (i < BB * HH) {
    hbuf0[i] = f2b(h0in[i]);            // slot 0 = H0(0)
    hbuf1[i] = f2b(h0in[BB * HH + i]);  // slot 0 = H1(0)
  }
}

// ---------------- phase A: xg0 = bf16(x @ W_ih0^T + b_ih0) ----------------

__global__ __launch_bounds__(256) void gemm_xg_k(
    const u16* __restrict__ A, const u16* __restrict__ Wt,
    const float* __restrict__ bias, u16* __restrict__ C) {
  const int bm = blockIdx.x / 24;
  const int bn = blockIdx.x % 24;
  const int m0 = bm * 128, n0 = bn * 128;
  __shared__ __align__(16) u16 al[128 * 40];
  __shared__ __align__(16) u16 bl[128 * 40];
  const int tid = threadIdx.x;
  const int w = tid >> 6, l = tid & 63;
  const int wr = w >> 1, wc = w & 1;
  const int c0 = tid, c1 = tid + 256;
  const int r0 = c0 >> 2, s0 = c0 & 3, r1 = c1 >> 2, s1 = c1 & 3;

  const f32x4 fzero = {0.f, 0.f, 0.f, 0.f};
  f32x4 acc[4][4];
#pragma unroll
  for (int i = 0; i < 4; ++i)
#pragma unroll
    for (int j = 0; j < 4; ++j) acc[i][j] = fzero;

  const u16* a0p = A + (size_t)(m0 + r0) * 1024 + s0 * 8;
  const u16* a1p = A + (size_t)(m0 + r1) * 1024 + s1 * 8;
  const u16* b0p = Wt + (size_t)(n0 + r0) * 1024 + s0 * 8;
  const u16* b1p = Wt + (size_t)(n0 + r1) * 1024 + s1 * 8;

  int4 va0 = *(const int4*)(a0p);
  int4 va1 = *(const int4*)(a1p);
  int4 vb0 = *(const int4*)(b0p);
  int4 vb1 = *(const int4*)(b1p);

  for (int kt = 0; kt < 32; ++kt) {
    __syncthreads();
    *(int4*)&al[r0 * 40 + s0 * 8] = va0;
    *(int4*)&al[r1 * 40 + s1 * 8] = va1;
    *(int4*)&bl[r0 * 40 + s0 * 8] = vb0;
    *(int4*)&bl[r1 * 40 + s1 * 8] = vb1;
    __syncthreads();
    if (kt < 31) {
      va0 = *(const int4*)(a0p + (kt + 1) * 32);
      va1 = *(const int4*)(a1p + (kt + 1) * 32);
      vb0 = *(const int4*)(b0p + (kt + 1) * 32);
      vb1 = *(const int4*)(b1p + (kt + 1) * 32);
    }
    short8 af[4], bf[4];
#pragma unroll
    for (int i = 0; i < 4; ++i)
      af[i] = *(const short8*)&al[(wr * 64 + i * 16 + (l & 15)) * 40 + (l >> 4) * 8];
#pragma unroll
    for (int j = 0; j < 4; ++j)
      bf[j] = *(const short8*)&bl[(wc * 64 + j * 16 + (l & 15)) * 40 + (l >> 4) * 8];
#pragma unroll
    for (int i = 0; i < 4; ++i)
#pragma unroll
      for (int j = 0; j < 4; ++j)
        acc[i][j] = __builtin_amdgcn_mfma_f32_16x16x32_bf16(af[i], bf[j], acc[i][j], 0, 0, 0);
  }

#pragma unroll
  for (int i = 0; i < 4; ++i) {
#pragma unroll
    for (int j = 0; j < 4; ++j) {
      int col = n0 + wc * 64 + j * 16 + (l & 15);
      float bv = bias[col];
#pragma unroll
      for (int q = 0; q < 4; ++q) {
        int row = m0 + wr * 64 + i * 16 + (l >> 4) * 4 + q;
        C[(size_t)row * G3 + col] = f2b(acc[i][j][q] + bv);
      }
    }
  }
}

// ---------------- persistent fused scan, v10: 3 decoupled 1-GEMM groups ----
//  p0 (blk 0..63,   16 cols): layer0 step t, t=0..511. Needs flags0>=t.
//     Reads hbuf0[t] (cached; renamed), writes hbuf0[t+1] (sc1). flags0=t+1.
//  p1 (blk 64..127, 16 cols): xg1 producer, t=1..512. Needs flags0>=t
//     (p0 ahead: pre-satisfied) and ring slot free (flags2min>=t-RING,
//     pre-satisfied). Reads hbuf0[t] cached; writes xg1ring[t&7] f32 sc1.
//     flags1=t. Runs ahead of p2.
//  p2 (blk 128..191,16 cols): layer1 step, t=1..512. Needs flags1>=t
//     (p1 ahead: pre-satisfied) and own flags2>=t-1. Reads hbuf1[t-1]
//     cached (renamed) + xg1ring[t&7] via sc1 (ring reuse => must bypass
//     L2), writes hbuf1[t] sc1. flags2=t.
// Critical path: each group's own 1-GEMM self-chain.

__global__ __launch_bounds__(256, 1) void gru_scan10_k(
    const u16* __restrict__ xg0,
    const u16* __restrict__ whh0, const u16* __restrict__ wih1,
    const u16* __restrict__ whh1,
    const float* __restrict__ bhh0, const float* __restrict__ bih1,
    const float* __restrict__ bhh1,
    const float* __restrict__ h0in,
    u16* __restrict__ hbuf0, u16* __restrict__ hbuf1,
    float* __restrict__ xg1ring, float* __restrict__ out,
    unsigned* __restrict__ flags) {
  const int blk = blockIdx.x;
  const int grp = blk >> 6;          // 0,1,2
  const int sub = blk & 63;
  const int tid = threadIdx.x;
  const int w = tid >> 6, l = tid & 63;
  const int lrow = l & 15;
  const int kb = (l >> 4) * 8;
  const int myrow0 = w * 16 + (l >> 4) * 4;
  const size_t arow = (size_t)(w * 16 + lrow) * HH + kb;
  const f32x4 fzero = {0.f, 0.f, 0.f, 0.f};

  __shared__ __align__(16) u16 wlds[48 * 1024];
  {
    const u16* Wsrc = (grp == 0) ? whh0 : (grp == 1) ? wih1 : whh1;
    for (int i = tid; i < 6144; i += 256) {
      int r = i >> 7;
      int c = i & 127;
      int g = r >> 4;
      int wrow = g * HH + sub * 16 + (r & 15);
      int4 v = *(const int4*)(Wsrc + (size_t)wrow * 1024 + c * 8);
      int idx = r * 1024 + ((c * 8) ^ ((r & 7) << 3));
      *(int4*)&wlds[idx] = v;
    }
  }
  __syncthreads();
  // one-time cross-replay staleness guard (renamed slots reused across graph
  // replays; W already safe in LDS)
  __builtin_amdgcn_fence(__ATOMIC_ACQUIRE, "agent");

  const int j = sub * 16 + lrow;
  const int sx = (lrow & 7) << 3;

  if (grp == 0) {
    const float bhr = bhh0[j], bhz = bhh0[HH + j], bhn = bhh0[2 * HH + j];
    float hreg[4];
#pragma unroll
    for (int q = 0; q < 4; ++q) hreg[q] = h0in[(myrow0 + q) * HH + j];

    for (int t = 0; t < TT; ++t) {
      // hoist xg0 loads: address-known, latency hides under the poll
      u16 xrv[4], xzv[4], xnv[4];
      const u16* xp = xg0 + (size_t)t * BB * G3;
#pragma unroll
      for (int q = 0; q < 4; ++q) {
        const u16* rp = xp + (size_t)(myrow0 + q) * G3;
        xrv[q] = rp[j]; xzv[q] = rp[HH + j]; xnv[q] = rp[2 * HH + j];
      }
      if (t > 0) {
        if (tid < 64) {
          for (;;) {
            unsigned a0 = ld_u32_agent(&flags[l * FSTRIDE]);
            if (__all(a0 >= (unsigned)t)) break;
            __builtin_amdgcn_s_sleep(1);
          }
        }
        __syncthreads();
        __builtin_amdgcn_fence(__ATOMIC_ACQUIRE, "workgroup");
      }

      const u16* Ap = hbuf0 + (size_t)t * SLOT + arow;
      short8 ar[32];
#pragma unroll
      for (int ks = 0; ks < 32; ++ks) ar[ks] = *(const short8*)(Ap + ks * 32);

      f32x4 acc0 = fzero, acc1 = fzero, acc2 = fzero;
#pragma unroll
      for (int ks = 0; ks < 32; ++ks) {
        int ke = kb + ks * 32;
        short8 b0 = *(const short8*)&wlds[(lrow) * 1024 + (ke ^ sx)];
        short8 b1 = *(const short8*)&wlds[(16 + lrow) * 1024 + (ke ^ sx)];
        short8 b2 = *(const short8*)&wlds[(32 + lrow) * 1024 + (ke ^ sx)];
        acc0 = __builtin_amdgcn_mfma_f32_16x16x32_bf16(ar[ks], b0, acc0, 0, 0, 0);
        acc1 = __builtin_amdgcn_mfma_f32_16x16x32_bf16(ar[ks], b1, acc1, 0, 0, 0);
        acc2 = __builtin_amdgcn_mfma_f32_16x16x32_bf16(ar[ks], b2, acc2, 0, 0, 0);
      }

      u16* hbn = hbuf0 + (size_t)(t + 1) * SLOT;
#pragma unroll
      for (int q = 0; q < 4; ++q) {
        float rr = acc0[q] + bhr + b2f(xrv[q]);
        float zz = acc1[q] + bhz + b2f(xzv[q]);
        float nn = acc2[q] + bhn;
        float r = 1.f / (1.f + __expf(-rr));
        float z = 1.f / (1.f + __expf(-zz));
        float n = ftanh(b2f(xnv[q]) + r * nn);
        float hv = (1.f - z) * n + z * hreg[q];
        hreg[q] = hv;
        int hb = (int)f2b(hv);
        int nb = __shfl_xor(hb, 1);
        if ((l & 1) == 0) {
          unsigned pk = (unsigned)(u16)hb | (((unsigned)(u16)nb) << 16);
          st_u32_agent((unsigned*)(hbn + (size_t)(myrow0 + q) * HH + j), pk);
        }
      }

      __syncthreads();  // drain sc1 stores
      if (tid == 0) {
        __builtin_amdgcn_fence(__ATOMIC_RELEASE, "workgroup");
        st_u32_agent(&flags[blk * FSTRIDE], (unsigned)(t + 1));
      }
    }
#pragma unroll
    for (int q = 0; q < 4; ++q) out[(size_t)(myrow0 + q) * HH + j] = hreg[q];

  } else if (grp == 1) {
    const float bir = bih1[j], biz = bih1[HH + j], bin = bih1[2 * HH + j];

    for (int t = 1; t <= TT; ++t) {
      if (tid < 64) {
        for (;;) {
          unsigned a0 = ld_u32_agent(&flags[l * FSTRIDE]);
          unsigned a2 = ld_u32_agent(&flags[(128 + l) * FSTRIDE]);
          int ok = (a0 >= (unsigned)t) && ((int)a2 >= t - RING);
          if (__all(ok)) break;
          __builtin_amdgcn_s_sleep(1);
        }
      }
      __syncthreads();
      __builtin_amdgcn_fence(__ATOMIC_ACQUIRE, "workgroup");

      const u16* Ap = hbuf0 + (size_t)t * SLOT + arow;
      short8 ar[32];
#pragma unroll
      for (int ks = 0; ks < 32; ++ks) ar[ks] = *(const short8*)(Ap + ks * 32);

      f32x4 acc0 = fzero, acc1 = fzero, acc2 = fzero;
#pragma unroll
      for (int ks = 0; ks < 32; ++ks) {
        int ke = kb + ks * 32;
        short8 b0 = *(const short8*)&wlds[(lrow) * 1024 + (ke ^ sx)];
        short8 b1 = *(const short8*)&wlds[(16 + lrow) * 1024 + (ke ^ sx)];
        short8 b2 = *(const short8*)&wlds[(32 + lrow) * 1024 + (ke ^ sx)];
        acc0 = __builtin_amdgcn_mfma_f32_16x16x32_bf16(ar[ks], b0, acc0, 0, 0, 0);
        acc1 = __builtin_amdgcn_mfma_f32_16x16x32_bf16(ar[ks], b1, acc1, 0, 0, 0);
        acc2 = __builtin_amdgcn_mfma_f32_16x16x32_bf16(ar[ks], b2, acc2, 0, 0, 0);
      }

      float* ox = xg1ring + (size_t)(t & (RING - 1)) * (BB * G3);
#pragma unroll
      for (int q = 0; q < 4; ++q) {
        int row = myrow0 + q;
        st_u32_agent((unsigned*)(ox + (size_t)row * G3 + j), __float_as_uint(acc0[q] + bir));
        st_u32_agent((unsigned*)(ox + (size_t)row * G3 + HH + j), __float_as_uint(acc1[q] + biz));
        st_u32_agent((unsigned*)(ox + (size_t)row * G3 + 2 * HH + j), __float_as_uint(acc2[q] + bin));
      }

      __syncthreads();
      if (tid == 0) {
        __builtin_amdgcn_fence(__ATOMIC_RELEASE, "workgroup");
        st_u32_agent(&flags[blk * FSTRIDE], (unsigned)t);
      }
    }

  } else {
    const float bhr = bhh1[j], bhz = bhh1[HH + j], bhn = bhh1[2 * HH + j];
    float hreg[4];
#pragma unroll
    for (int q = 0; q < 4; ++q) hreg[q] = h0in[BB * HH + (myrow0 + q) * HH + j];

    for (int t = 1; t <= TT; ++t) {
      if (tid < 64) {
        for (;;) {
          unsigned a1 = ld_u32_agent(&flags[(64 + l) * FSTRIDE]);
          unsigned a2 = ld_u32_agent(&flags[(128 + l) * FSTRIDE]);
          int ok = (a1 >= (unsigned)t) && (a2 >= (unsigned)(t - 1));
          if (__all(ok)) break;
          __builtin_amdgcn_s_sleep(1);
        }
      }
      __syncthreads();
      __builtin_amdgcn_fence(__ATOMIC_ACQUIRE, "workgroup");

      // batch: A (cached, renamed) + xg1 ring (sc1, reused slots)
      const u16* Ap = hbuf1 + (size_t)(t - 1) * SLOT + arow;
      short8 ar[32];
#pragma unroll
      for (int ks = 0; ks < 32; ++ks) ar[ks] = *(const short8*)(Ap + ks * 32);
      const float* ox = xg1ring + (size_t)(t & (RING - 1)) * (BB * G3);
      float xg1v[3][4];
#pragma unroll
      for (int q = 0; q < 4; ++q) {
        const float* rp = ox + (size_t)(myrow0 + q) * G3;
        xg1v[0][q] = __uint_as_float(ld_u32_agent((const unsigned*)(rp + j)));
        xg1v[1][q] = __uint_as_float(ld_u32_agent((const unsigned*)(rp + HH + j)));
        xg1v[2][q] = __uint_as_float(ld_u32_agent((const unsigned*)(rp + 2 * HH + j)));
      }

      f32x4 acc0 = fzero, acc1 = fzero, acc2 = fzero;
#pragma unroll
      for (int ks = 0; ks < 32; ++ks) {
        int ke = kb + ks * 32;
        short8 b0 = *(const short8*)&wlds[(lrow) * 1024 + (ke ^ sx)];
        short8 b1 = *(const short8*)&wlds[(16 + lrow) * 1024 + (ke ^ sx)];
        short8 b2 = *(const short8*)&wlds[(32 + lrow) * 1024 + (ke ^ sx)];
        acc0 = __builtin_amdgcn_mfma_f32_16x16x32_bf16(ar[ks], b0, acc0, 0, 0, 0);
        acc1 = __builtin_amdgcn_mfma_f32_16x16x32_bf16(ar[ks], b1, acc1, 0, 0, 0);
        acc2 = __builtin_amdgcn_mfma_f32_16x16x32_bf16(ar[ks], b2, acc2, 0, 0, 0);
      }

      u16* hbn = hbuf1 + (size_t)t * SLOT;
#pragma unroll
      for (int q = 0; q < 4; ++q) {
        float rr = acc0[q] + bhr + xg1v[0][q];
        float zz = acc1[q] + bhz + xg1v[1][q];
        float nn = acc2[q] + bhn;
        float r = 1.f / (1.f + __expf(-rr));
        float z = 1.f / (1.f + __expf(-zz));
        float n = ftanh(xg1v[2][q] + r * nn);
        float hv = (1.f - z) * n + z * hreg[q];
        hreg[q] = hv;
        int hb = (int)f2b(hv);
        int nb = __shfl_xor(hb, 1);
        if ((l & 1) == 0) {
          unsigned pk = (unsigned)(u16)hb | (((unsigned)(u16)nb) << 16);
          st_u32_agent((unsigned*)(hbn + (size_t)(myrow0 + q) * HH + j), pk);
        }
      }

      __syncthreads();
      if (tid == 0) {
        __builtin_amdgcn_fence(__ATOMIC_RELEASE, "workgroup");
        st_u32_agent(&flags[blk * FSTRIDE], (unsigned)t);
      }
    }
#pragma unroll
    for (int q = 0; q < 4; ++q) out[BB * HH + (size_t)(myrow0 + q) * HH + j] = hreg[q];
  }
}

// ---------------- host ----------------

extern "C" void kernel_launch(void* const* d_in, const int* in_sizes, int n_in,
                              void* d_out, int out_size, void* d_ws, size_t ws_size,
                              hipStream_t stream) {
  const float* x   = (const float*)d_in[0];
  const float* h0  = (const float*)d_in[1];
  const float* wih = (const float*)d_in[2];
  const float* whh = (const float*)d_in[3];
  const float* bih = (const float*)d_in[4];
  const float* bhh = (const float*)d_in[5];
  float* out = (float*)d_out;

  char* ws = (char*)d_ws;
  size_t off = 0;
  auto alloc = [&](size_t bytes) -> void* {
    void* p = ws + off;
    off += (bytes + 255) & ~(size_t)255;
    return p;
  };
  u16* xg0   = (u16*)alloc((size_t)TT * BB * G3 * 2);        // 193 MB
  u16* wihb  = (u16*)alloc((size_t)2 * G3 * HH * 2);         // 12.6 MB
  u16* whhb  = (u16*)alloc((size_t)2 * G3 * HH * 2);         // 12.6 MB
  // union: xbf (64 MB, dead after gemm) overlaid by hbuf0/hbuf1 (134.5 MB)
  size_t hbytes = (size_t)2 * NS * SLOT * 2;
  size_t xbytes = (size_t)TT * BB * HH * 2;
  char* un = (char*)alloc(hbytes > xbytes ? hbytes : xbytes);
  u16* xbf   = (u16*)un;
  u16* hbuf0 = (u16*)un;
  u16* hbuf1 = hbuf0 + (size_t)NS * SLOT;
  float* xg1ring = (float*)alloc((size_t)RING * BB * G3 * 4);  // 6.3 MB
  unsigned* flags = (unsigned*)alloc(NBLK * FSTRIDE * 4);

  hipMemsetAsync(flags, 0, NBLK * FSTRIDE * 4, stream);
  f32_to_bf16_k<<<2048, 256, 0, stream>>>(x, xbf, TT * BB * HH);
  f32_to_bf16_k<<<512, 256, 0, stream>>>(wih, wihb, 2 * G3 * HH);
  f32_to_bf16_k<<<512, 256, 0, stream>>>(whh, whhb, 2 * G3 * HH);

  gemm_xg_k<<<6144, 256, 0, stream>>>(xbf, wihb, bih, xg0);

  // init h AFTER gemm: hbuf aliases xbf
  init_h_k<<<256, 256, 0, stream>>>(h0, hbuf0, hbuf1);

  gru_scan10_k<<<NBLK, 256, 0, stream>>>(xg0,
                                         whhb, wihb + (size_t)G3 * HH, whhb + (size_t)G3 * HH,
                                         bhh, bih + G3, bhh + G3, h0,
                                         hbuf0, hbuf1, xg1ring, out, flags);
}

// Round 12
// 4422.406 us; speedup vs baseline: 1.2533x; 1.0097x over previous
//
#include <hip/hip_runtime.h>

typedef unsigned short u16;
typedef unsigned long long u64;
typedef __attribute__((ext_vector_type(8))) short short8;
typedef __attribute__((ext_vector_type(4))) float f32x4;

#define HH 1024
#define BB 64
#define TT 512
#define G3 3072
#define NBLK 192
#define NS 513                 // h time-slots (renamed buffers)
#define SLOT (BB * HH)         // elems per h slot
#define FSTRIDE 32             // flag padding: one 128B line per block
#define RING 8                 // xg1 ring depth

__device__ __forceinline__ u16 f2b(float f) {
  unsigned u = __float_as_uint(f);
  unsigned r = (u + 0x7fffu + ((u >> 16) & 1u)) >> 16;
  return (u16)r;
}
__device__ __forceinline__ float b2f(u16 h) {
  return __uint_as_float(((unsigned)h) << 16);
}
__device__ __forceinline__ float ftanh(float x) {
  x = fminf(15.f, fmaxf(-15.f, x));
  float e = __expf(2.f * x);
  return (e - 1.f) / (e + 1.f);
}

__device__ __forceinline__ void st_u32_agent(unsigned* p, unsigned v) {
  __hip_atomic_store(p, v, __ATOMIC_RELAXED, __HIP_MEMORY_SCOPE_AGENT);
}
__device__ __forceinline__ unsigned ld_u32_agent(const unsigned* p) {
  return __hip_atomic_load(p, __ATOMIC_RELAXED, __HIP_MEMORY_SCOPE_AGENT);
}

// ---------------- elementwise converts / init ----------------

__global__ void f32_to_bf16_k(const float* __restrict__ s, u16* __restrict__ d, int n) {
  int stride = gridDim.x * blockDim.x * 4;
  for (int i = (blockIdx.x * blockDim.x + threadIdx.x) * 4; i < n; i += stride) {
    float4 v = *(const float4*)(s + i);
    uint2 p;
    p.x = (unsigned)f2b(v.x) | ((unsigned)f2b(v.y) << 16);
    p.y = (unsigned)f2b(v.z) | ((unsigned)f2b(v.w) << 16);
    *(uint2*)(d + i) = p;
  }
}

__global__ void init_h_k(const float* __restrict__ h0in, u16* __restrict__ hbuf0,
                         u16* __restrict__ hbuf1) {
  int i = blockIdx.x * blockDim.x + threadIdx.x;
  if (i < BB * HH) {
    hbuf0[i] = f2b(h0in[i]);            // slot 0 = H0(0)
    hbuf1[i] = f2b(h0in[BB * HH + i]);  // slot 0 = H1(0)
  }
}

// ---------------- phase A: xg0 = bf16(x @ W_ih0^T + b_ih0) ----------------

__global__ __launch_bounds__(256) void gemm_xg_k(
    const u16* __restrict__ A, const u16* __restrict__ Wt,
    const float* __restrict__ bias, u16* __restrict__ C) {
  const int bm = blockIdx.x / 24;
  const int bn = blockIdx.x % 24;
  const int m0 = bm * 128, n0 = bn * 128;
  __shared__ __align__(16) u16 al[128 * 40];
  __shared__ __align__(16) u16 bl[128 * 40];
  const int tid = threadIdx.x;
  const int w = tid >> 6, l = tid & 63;
  const int wr = w >> 1, wc = w & 1;
  const int c0 = tid, c1 = tid + 256;
  const int r0 = c0 >> 2, s0 = c0 & 3, r1 = c1 >> 2, s1 = c1 & 3;

  const f32x4 fzero = {0.f, 0.f, 0.f, 0.f};
  f32x4 acc[4][4];
#pragma unroll
  for (int i = 0; i < 4; ++i)
#pragma unroll
    for (int j = 0; j < 4; ++j) acc[i][j] = fzero;

  const u16* a0p = A + (size_t)(m0 + r0) * 1024 + s0 * 8;
  const u16* a1p = A + (size_t)(m0 + r1) * 1024 + s1 * 8;
  const u16* b0p = Wt + (size_t)(n0 + r0) * 1024 + s0 * 8;
  const u16* b1p = Wt + (size_t)(n0 + r1) * 1024 + s1 * 8;

  int4 va0 = *(const int4*)(a0p);
  int4 va1 = *(const int4*)(a1p);
  int4 vb0 = *(const int4*)(b0p);
  int4 vb1 = *(const int4*)(b1p);

  for (int kt = 0; kt < 32; ++kt) {
    __syncthreads();
    *(int4*)&al[r0 * 40 + s0 * 8] = va0;
    *(int4*)&al[r1 * 40 + s1 * 8] = va1;
    *(int4*)&bl[r0 * 40 + s0 * 8] = vb0;
    *(int4*)&bl[r1 * 40 + s1 * 8] = vb1;
    __syncthreads();
    if (kt < 31) {
      va0 = *(const int4*)(a0p + (kt + 1) * 32);
      va1 = *(const int4*)(a1p + (kt + 1) * 32);
      vb0 = *(const int4*)(b0p + (kt + 1) * 32);
      vb1 = *(const int4*)(b1p + (kt + 1) * 32);
    }
    short8 af[4], bf[4];
#pragma unroll
    for (int i = 0; i < 4; ++i)
      af[i] = *(const short8*)&al[(wr * 64 + i * 16 + (l & 15)) * 40 + (l >> 4) * 8];
#pragma unroll
    for (int j = 0; j < 4; ++j)
      bf[j] = *(const short8*)&bl[(wc * 64 + j * 16 + (l & 15)) * 40 + (l >> 4) * 8];
#pragma unroll
    for (int i = 0; i < 4; ++i)
#pragma unroll
      for (int j = 0; j < 4; ++j)
        acc[i][j] = __builtin_amdgcn_mfma_f32_16x16x32_bf16(af[i], bf[j], acc[i][j], 0, 0, 0);
  }

#pragma unroll
  for (int i = 0; i < 4; ++i) {
#pragma unroll
    for (int j = 0; j < 4; ++j) {
      int col = n0 + wc * 64 + j * 16 + (l & 15);
      float bv = bias[col];
#pragma unroll
      for (int q = 0; q < 4; ++q) {
        int row = m0 + wr * 64 + i * 16 + (l >> 4) * 4 + q;
        C[(size_t)row * G3 + col] = f2b(acc[i][j][q] + bv);
      }
    }
  }
}

// ---------------- persistent fused scan, v11 ----------------
// Same 3 decoupled 1-GEMM groups as R11 (proven 8.1 us/step), with:
//  * xg1 ring packed bf16 (2 cols per u32): halves p1 store-drain bytes and
//    p2 ring-load traffic (f32 402 MB/scan -> bf16 201 MB).
//  * busy-poll (no s_sleep) on the detect edge.
//  p0 (blk 0..63):   layer0 step t, t=0..511. flags0.
//  p1 (blk 64..127): xg1 producer, t=1..512. flags0 + ring backpressure.
//  p2 (blk 128..191):layer1 step,  t=1..512. flags1 + own flags2.

__global__ __launch_bounds__(256, 1) void gru_scan11_k(
    const u16* __restrict__ xg0,
    const u16* __restrict__ whh0, const u16* __restrict__ wih1,
    const u16* __restrict__ whh1,
    const float* __restrict__ bhh0, const float* __restrict__ bih1,
    const float* __restrict__ bhh1,
    const float* __restrict__ h0in,
    u16* __restrict__ hbuf0, u16* __restrict__ hbuf1,
    u16* __restrict__ xg1ring, float* __restrict__ out,
    unsigned* __restrict__ flags) {
  const int blk = blockIdx.x;
  const int grp = blk >> 6;          // 0,1,2
  const int sub = blk & 63;
  const int tid = threadIdx.x;
  const int w = tid >> 6, l = tid & 63;
  const int lrow = l & 15;
  const int kb = (l >> 4) * 8;
  const int myrow0 = w * 16 + (l >> 4) * 4;
  const size_t arow = (size_t)(w * 16 + lrow) * HH + kb;
  const f32x4 fzero = {0.f, 0.f, 0.f, 0.f};

  __shared__ __align__(16) u16 wlds[48 * 1024];
  {
    const u16* Wsrc = (grp == 0) ? whh0 : (grp == 1) ? wih1 : whh1;
    for (int i = tid; i < 6144; i += 256) {
      int r = i >> 7;
      int c = i & 127;
      int g = r >> 4;
      int wrow = g * HH + sub * 16 + (r & 15);
      int4 v = *(const int4*)(Wsrc + (size_t)wrow * 1024 + c * 8);
      int idx = r * 1024 + ((c * 8) ^ ((r & 7) << 3));
      *(int4*)&wlds[idx] = v;
    }
  }
  __syncthreads();
  // one-time cross-replay staleness guard (renamed slots reused across graph
  // replays; W already safe in LDS)
  __builtin_amdgcn_fence(__ATOMIC_ACQUIRE, "agent");

  const int j = sub * 16 + lrow;
  const int sx = (lrow & 7) << 3;

  if (grp == 0) {
    const float bhr = bhh0[j], bhz = bhh0[HH + j], bhn = bhh0[2 * HH + j];
    float hreg[4];
#pragma unroll
    for (int q = 0; q < 4; ++q) hreg[q] = h0in[(myrow0 + q) * HH + j];

    for (int t = 0; t < TT; ++t) {
      // hoist xg0 loads: address-known, latency hides under the poll
      u16 xrv[4], xzv[4], xnv[4];
      const u16* xp = xg0 + (size_t)t * BB * G3;
#pragma unroll
      for (int q = 0; q < 4; ++q) {
        const u16* rp = xp + (size_t)(myrow0 + q) * G3;
        xrv[q] = rp[j]; xzv[q] = rp[HH + j]; xnv[q] = rp[2 * HH + j];
      }
      if (t > 0) {
        if (tid < 64) {
          for (;;) {
            unsigned a0 = ld_u32_agent(&flags[l * FSTRIDE]);
            if (__all(a0 >= (unsigned)t)) break;
          }
        }
        __syncthreads();
        __builtin_amdgcn_fence(__ATOMIC_ACQUIRE, "workgroup");
      }

      const u16* Ap = hbuf0 + (size_t)t * SLOT + arow;
      short8 ar[32];
#pragma unroll
      for (int ks = 0; ks < 32; ++ks) ar[ks] = *(const short8*)(Ap + ks * 32);

      f32x4 acc0 = fzero, acc1 = fzero, acc2 = fzero;
#pragma unroll
      for (int ks = 0; ks < 32; ++ks) {
        int ke = kb + ks * 32;
        short8 b0 = *(const short8*)&wlds[(lrow) * 1024 + (ke ^ sx)];
        short8 b1 = *(const short8*)&wlds[(16 + lrow) * 1024 + (ke ^ sx)];
        short8 b2 = *(const short8*)&wlds[(32 + lrow) * 1024 + (ke ^ sx)];
        acc0 = __builtin_amdgcn_mfma_f32_16x16x32_bf16(ar[ks], b0, acc0, 0, 0, 0);
        acc1 = __builtin_amdgcn_mfma_f32_16x16x32_bf16(ar[ks], b1, acc1, 0, 0, 0);
        acc2 = __builtin_amdgcn_mfma_f32_16x16x32_bf16(ar[ks], b2, acc2, 0, 0, 0);
      }

      u16* hbn = hbuf0 + (size_t)(t + 1) * SLOT;
#pragma unroll
      for (int q = 0; q < 4; ++q) {
        float rr = acc0[q] + bhr + b2f(xrv[q]);
        float zz = acc1[q] + bhz + b2f(xzv[q]);
        float nn = acc2[q] + bhn;
        float r = 1.f / (1.f + __expf(-rr));
        float z = 1.f / (1.f + __expf(-zz));
        float n = ftanh(b2f(xnv[q]) + r * nn);
        float hv = (1.f - z) * n + z * hreg[q];
        hreg[q] = hv;
        int hb = (int)f2b(hv);
        int nb = __shfl_xor(hb, 1);
        if ((l & 1) == 0) {
          unsigned pk = (unsigned)(u16)hb | (((unsigned)(u16)nb) << 16);
          st_u32_agent((unsigned*)(hbn + (size_t)(myrow0 + q) * HH + j), pk);
        }
      }

      __syncthreads();  // drain sc1 stores
      if (tid == 0) {
        __builtin_amdgcn_fence(__ATOMIC_RELEASE, "workgroup");
        st_u32_agent(&flags[blk * FSTRIDE], (unsigned)(t + 1));
      }
    }
#pragma unroll
    for (int q = 0; q < 4; ++q) out[(size_t)(myrow0 + q) * HH + j] = hreg[q];

  } else if (grp == 1) {
    const float bir = bih1[j], biz = bih1[HH + j], bin = bih1[2 * HH + j];

    for (int t = 1; t <= TT; ++t) {
      if (tid < 64) {
        for (;;) {
          unsigned a0 = ld_u32_agent(&flags[l * FSTRIDE]);
          unsigned a2 = ld_u32_agent(&flags[(128 + l) * FSTRIDE]);
          int ok = (a0 >= (unsigned)t) && ((int)a2 >= t - RING);
          if (__all(ok)) break;
        }
      }
      __syncthreads();
      __builtin_amdgcn_fence(__ATOMIC_ACQUIRE, "workgroup");

      const u16* Ap = hbuf0 + (size_t)t * SLOT + arow;
      short8 ar[32];
#pragma unroll
      for (int ks = 0; ks < 32; ++ks) ar[ks] = *(const short8*)(Ap + ks * 32);

      f32x4 acc0 = fzero, acc1 = fzero, acc2 = fzero;
#pragma unroll
      for (int ks = 0; ks < 32; ++ks) {
        int ke = kb + ks * 32;
        short8 b0 = *(const short8*)&wlds[(lrow) * 1024 + (ke ^ sx)];
        short8 b1 = *(const short8*)&wlds[(16 + lrow) * 1024 + (ke ^ sx)];
        short8 b2 = *(const short8*)&wlds[(32 + lrow) * 1024 + (ke ^ sx)];
        acc0 = __builtin_amdgcn_mfma_f32_16x16x32_bf16(ar[ks], b0, acc0, 0, 0, 0);
        acc1 = __builtin_amdgcn_mfma_f32_16x16x32_bf16(ar[ks], b1, acc1, 0, 0, 0);
        acc2 = __builtin_amdgcn_mfma_f32_16x16x32_bf16(ar[ks], b2, acc2, 0, 0, 0);
      }

      // packed bf16 ring write: even lane stores {col j (lo), col j+1 (hi)}
      u16* ox = xg1ring + (size_t)(t & (RING - 1)) * (BB * G3);
#pragma unroll
      for (int q = 0; q < 4; ++q) {
        int row = myrow0 + q;
        int a0v = (int)f2b(acc0[q] + bir); int a0n = __shfl_xor(a0v, 1);
        int a1v = (int)f2b(acc1[q] + biz); int a1n = __shfl_xor(a1v, 1);
        int a2v = (int)f2b(acc2[q] + bin); int a2n = __shfl_xor(a2v, 1);
        if ((l & 1) == 0) {
          st_u32_agent((unsigned*)(ox + (size_t)row * G3 + j),
                       (unsigned)(u16)a0v | (((unsigned)(u16)a0n) << 16));
          st_u32_agent((unsigned*)(ox + (size_t)row * G3 + HH + j),
                       (unsigned)(u16)a1v | (((unsigned)(u16)a1n) << 16));
          st_u32_agent((unsigned*)(ox + (size_t)row * G3 + 2 * HH + j),
                       (unsigned)(u16)a2v | (((unsigned)(u16)a2n) << 16));
        }
      }

      __syncthreads();
      if (tid == 0) {
        __builtin_amdgcn_fence(__ATOMIC_RELEASE, "workgroup");
        st_u32_agent(&flags[blk * FSTRIDE], (unsigned)t);
      }
    }

  } else {
    const float bhr = bhh1[j], bhz = bhh1[HH + j], bhn = bhh1[2 * HH + j];
    float hreg[4];
#pragma unroll
    for (int q = 0; q < 4; ++q) hreg[q] = h0in[BB * HH + (myrow0 + q) * HH + j];
    const int jpair = j & ~1;           // even base col of this lane's pair
    const int sel = (j & 1) * 16;       // extract shift

    for (int t = 1; t <= TT; ++t) {
      if (tid < 64) {
        for (;;) {
          unsigned a1 = ld_u32_agent(&flags[(64 + l) * FSTRIDE]);
          unsigned a2 = ld_u32_agent(&flags[(128 + l) * FSTRIDE]);
          int ok = (a1 >= (unsigned)t) && (a2 >= (unsigned)(t - 1));
          if (__all(ok)) break;
        }
      }
      __syncthreads();
      __builtin_amdgcn_fence(__ATOMIC_ACQUIRE, "workgroup");

      // batch: A (cached, renamed) + xg1 ring (sc1 packed bf16)
      const u16* Ap = hbuf1 + (size_t)(t - 1) * SLOT + arow;
      short8 ar[32];
#pragma unroll
      for (int ks = 0; ks < 32; ++ks) ar[ks] = *(const short8*)(Ap + ks * 32);
      const u16* ox = xg1ring + (size_t)(t & (RING - 1)) * (BB * G3);
      float xg1v[3][4];
#pragma unroll
      for (int q = 0; q < 4; ++q) {
        const u16* rp = ox + (size_t)(myrow0 + q) * G3;
        unsigned pr = ld_u32_agent((const unsigned*)(rp + jpair));
        unsigned pz = ld_u32_agent((const unsigned*)(rp + HH + jpair));
        unsigned pn = ld_u32_agent((const unsigned*)(rp + 2 * HH + jpair));
        xg1v[0][q] = b2f((u16)(pr >> sel));
        xg1v[1][q] = b2f((u16)(pz >> sel));
        xg1v[2][q] = b2f((u16)(pn >> sel));
      }

      f32x4 acc0 = fzero, acc1 = fzero, acc2 = fzero;
#pragma unroll
      for (int ks = 0; ks < 32; ++ks) {
        int ke = kb + ks * 32;
        short8 b0 = *(const short8*)&wlds[(lrow) * 1024 + (ke ^ sx)];
        short8 b1 = *(const short8*)&wlds[(16 + lrow) * 1024 + (ke ^ sx)];
        short8 b2 = *(const short8*)&wlds[(32 + lrow) * 1024 + (ke ^ sx)];
        acc0 = __builtin_amdgcn_mfma_f32_16x16x32_bf16(ar[ks], b0, acc0, 0, 0, 0);
        acc1 = __builtin_amdgcn_mfma_f32_16x16x32_bf16(ar[ks], b1, acc1, 0, 0, 0);
        acc2 = __builtin_amdgcn_mfma_f32_16x16x32_bf16(ar[ks], b2, acc2, 0, 0, 0);
      }

      u16* hbn = hbuf1 + (size_t)t * SLOT;
#pragma unroll
      for (int q = 0; q < 4; ++q) {
        float rr = acc0[q] + bhr + xg1v[0][q];
        float zz = acc1[q] + bhz + xg1v[1][q];
        float nn = acc2[q] + bhn;
        float r = 1.f / (1.f + __expf(-rr));
        float z = 1.f / (1.f + __expf(-zz));
        float n = ftanh(xg1v[2][q] + r * nn);
        float hv = (1.f - z) * n + z * hreg[q];
        hreg[q] = hv;
        int hb = (int)f2b(hv);
        int nb = __shfl_xor(hb, 1);
        if ((l & 1) == 0) {
          unsigned pk = (unsigned)(u16)hb | (((unsigned)(u16)nb) << 16);
          st_u32_agent((unsigned*)(hbn + (size_t)(myrow0 + q) * HH + j), pk);
        }
      }

      __syncthreads();
      if (tid == 0) {
        __builtin_amdgcn_fence(__ATOMIC_RELEASE, "workgroup");
        st_u32_agent(&flags[blk * FSTRIDE], (unsigned)t);
      }
    }
#pragma unroll
    for (int q = 0; q < 4; ++q) out[BB * HH + (size_t)(myrow0 + q) * HH + j] = hreg[q];
  }
}

// ---------------- host ----------------

extern "C" void kernel_launch(void* const* d_in, const int* in_sizes, int n_in,
                              void* d_out, int out_size, void* d_ws, size_t ws_size,
                              hipStream_t stream) {
  const float* x   = (const float*)d_in[0];
  const float* h0  = (const float*)d_in[1];
  const float* wih = (const float*)d_in[2];
  const float* whh = (const float*)d_in[3];
  const float* bih = (const float*)d_in[4];
  const float* bhh = (const float*)d_in[5];
  float* out = (float*)d_out;

  char* ws = (char*)d_ws;
  size_t off = 0;
  auto alloc = [&](size_t bytes) -> void* {
    void* p = ws + off;
    off += (bytes + 255) & ~(size_t)255;
    return p;
  };
  u16* xg0   = (u16*)alloc((size_t)TT * BB * G3 * 2);        // 193 MB
  u16* wihb  = (u16*)alloc((size_t)2 * G3 * HH * 2);         // 12.6 MB
  u16* whhb  = (u16*)alloc((size_t)2 * G3 * HH * 2);         // 12.6 MB
  // union: xbf (64 MB, dead after gemm) overlaid by hbuf0/hbuf1 (134.5 MB)
  size_t hbytes = (size_t)2 * NS * SLOT * 2;
  size_t xbytes = (size_t)TT * BB * HH * 2;
  char* un = (char*)alloc(hbytes > xbytes ? hbytes : xbytes);
  u16* xbf   = (u16*)un;
  u16* hbuf0 = (u16*)un;
  u16* hbuf1 = hbuf0 + (size_t)NS * SLOT;
  u16* xg1ring = (u16*)alloc((size_t)RING * BB * G3 * 2);    // 3.1 MB (bf16)
  unsigned* flags = (unsigned*)alloc(NBLK * FSTRIDE * 4);

  hipMemsetAsync(flags, 0, NBLK * FSTRIDE * 4, stream);
  f32_to_bf16_k<<<2048, 256, 0, stream>>>(x, xbf, TT * BB * HH);
  f32_to_bf16_k<<<512, 256, 0, stream>>>(wih, wihb, 2 * G3 * HH);
  f32_to_bf16_k<<<512, 256, 0, stream>>>(whh, whhb, 2 * G3 * HH);

  gemm_xg_k<<<6144, 256, 0, stream>>>(xbf, wihb, bih, xg0);

  // init h AFTER gemm: hbuf aliases xbf
  init_h_k<<<256, 256, 0, stream>>>(h0, hbuf0, hbuf1);

  gru_scan11_k<<<NBLK, 256, 0, stream>>>(xg0,
                                         whhb, wihb + (size_t)G3 * HH, whhb + (size_t)G3 * HH,
                                         bhh, bih + G3, bhh + G3, h0,
                                         hbuf0, hbuf1, xg1ring, out, flags);
}